// Round 2
// baseline (179.514 us; speedup 1.0000x reference)
//
#include <hip/hip_runtime.h>

// Embedding gather: out[t, :] = e[token_ids[t], :]
// token_ids: (2,4096) int32 -> 8192 tokens
// e: (32000, 1024) float32
// out: (2, 4096, 1024) float32
//
// 16 tokens per 256-thread block (grid = 512): each thread moves one 16B
// vector per token -> 16 independent gather loads in flight per wave before
// any wait (vmcnt max is 63, plenty). ids fetched as 4x int4 (64B) so all
// row indices arrive in one dependency round-trip. Exactly 2 blocks/CU,
// no tail. Non-temporal stores keep the write-once output from evicting
// embedding rows from L2.

#define DIM 1024
#define TOK_PER_BLOCK 16

typedef float f32x4 __attribute__((ext_vector_type(4)));
typedef int   i32x4 __attribute__((ext_vector_type(4)));

__global__ __launch_bounds__(256) void embedding_gather_kernel(
    const int* __restrict__ ids,
    const float* __restrict__ e,
    float* __restrict__ out,
    int n_tokens)
{
    const int t0 = blockIdx.x * TOK_PER_BLOCK;
    const int tid = threadIdx.x;

    // All 16 row indices in 4 vector loads (64B, one round-trip)
    i32x4 idv[TOK_PER_BLOCK / 4];
    const i32x4* idp = (const i32x4*)(ids + t0);
#pragma unroll
    for (int i = 0; i < TOK_PER_BLOCK / 4; ++i)
        idv[i] = idp[i];

    // 16 independent 16B gather loads in flight before any wait
    f32x4 v[TOK_PER_BLOCK];
#pragma unroll
    for (int i = 0; i < TOK_PER_BLOCK; ++i) {
        const int row = idv[i / 4][i % 4];
        const f32x4* src = (const f32x4*)(e + (size_t)row * DIM);
        v[i] = src[tid];
    }

    // Non-temporal stores: output is write-once, keep it out of L2.
    // Compiler interleaves these with load completions via vmcnt(N).
#pragma unroll
    for (int i = 0; i < TOK_PER_BLOCK; ++i) {
        f32x4* dst = (f32x4*)(out + (size_t)(t0 + i) * DIM);
        __builtin_nontemporal_store(v[i], dst + tid);
    }
}

extern "C" void kernel_launch(void* const* d_in, const int* in_sizes, int n_in,
                              void* d_out, int out_size, void* d_ws, size_t ws_size,
                              hipStream_t stream)
{
    const int* ids = (const int*)d_in[0];     // (2,4096) int32
    const float* e = (const float*)d_in[1];   // (32000,1024) fp32
    float* out = (float*)d_out;               // (2,4096,1024) fp32

    const int n_tokens = in_sizes[0];          // 8192
    const int grid = n_tokens / TOK_PER_BLOCK; // 512

    embedding_gather_kernel<<<grid, 256, 0, stream>>>(ids, e, out, n_tokens);
}